// Round 11
// baseline (323.873 us; speedup 1.0000x reference)
//
#include <hip/hip_runtime.h>
#include <hip/hip_fp16.h>
#include <math.h>

#define NN 50000
#define DD 128
#define NCLS 40
#define EPSV 1e-8f

__device__ __forceinline__ float waveReduceSum(float v) {
    for (int off = 32; off > 0; off >>= 1) v += __shfl_xor(v, off, 64);
    return v;
}

__device__ __forceinline__ float bcastlane0(float v) {
    return __int_as_float(__builtin_amdgcn_readfirstlane(__float_as_int(v)));
}

__device__ __forceinline__ float h_lo(unsigned int w) {
    return __half2float(__ushort_as_half((unsigned short)(w & 0xffffu)));
}
__device__ __forceinline__ float h_hi(unsigned int w) {
    return __half2float(__ushort_as_half((unsigned short)(w >> 16)));
}
__device__ __forceinline__ unsigned int h_pack(float a, float b) {
    return (unsigned int)__half_as_ushort(__float2half(a)) |
           ((unsigned int)__half_as_ushort(__float2half(b)) << 16);
}

// ---------------- CSR build ----------------

__global__ void hist_kernel(const int* __restrict__ erow, int* __restrict__ cnt, int E) {
    for (int e = blockIdx.x * blockDim.x + threadIdx.x; e < E; e += gridDim.x * blockDim.x)
        atomicAdd(&cnt[erow[e]], 1);
}

__global__ void scan1_kernel(const int* __restrict__ cnt, int* __restrict__ rs,
                             int* __restrict__ bsum, int n) {
    __shared__ int sdata[256];
    int tid = threadIdx.x;
    int gid = blockIdx.x * 256 + tid;
    int v = (gid < n) ? cnt[gid] : 0;
    sdata[tid] = v;
    __syncthreads();
    for (int off = 1; off < 256; off <<= 1) {
        int t = (tid >= off) ? sdata[tid - off] : 0;
        __syncthreads();
        sdata[tid] += t;
        __syncthreads();
    }
    if (gid < n) rs[gid] = sdata[tid] - v;
    if (tid == 255) bsum[blockIdx.x] = sdata[255];
}

__global__ void scan2_kernel(int* __restrict__ bsum, int nb) {
    __shared__ int sdata[256];
    int tid = threadIdx.x;
    int v = (tid < nb) ? bsum[tid] : 0;
    sdata[tid] = v;
    __syncthreads();
    for (int off = 1; off < 256; off <<= 1) {
        int t = (tid >= off) ? sdata[tid - off] : 0;
        __syncthreads();
        sdata[tid] += t;
        __syncthreads();
    }
    if (tid < nb) bsum[tid] = sdata[tid] - v;
}

__global__ void scan3_kernel(int* __restrict__ rs, const int* __restrict__ bsum, int n, int E) {
    int gid = blockIdx.x * 256 + threadIdx.x;
    if (gid < n) rs[gid] += bsum[blockIdx.x];
    else if (gid == n) rs[n] = E;
}

__global__ void fill_kernel(const int* __restrict__ erow, const int* __restrict__ ecol,
                            const float* __restrict__ ew, int* __restrict__ pos,
                            int* __restrict__ ecol_s, float* __restrict__ ew_s, int E) {
    for (int e = blockIdx.x * blockDim.x + threadIdx.x; e < E; e += gridDim.x * blockDim.x) {
        int r = erow[e];
        int p = atomicAdd(&pos[r], 1);
        ecol_s[p] = ecol[e];
        ew_s[p] = ew[e];
    }
}

// ---------------- W transpose (once per launch) ----------------
__global__ void transpose128(const float* __restrict__ W, float* __restrict__ Wt) {
    int idx = blockIdx.x * 256 + threadIdx.x;
    if (idx < 128 * 128) {
        int i = idx >> 7, k = idx & 127;
        Wt[k * 128 + i] = W[idx];
    }
}

// ---------------- fused linears (unchanged structure, fp16 output) ----------------
#define RPW 8
template <int PREEXP>
__global__ __launch_bounds__(256, 8) void linear_lorentz(
    const float* __restrict__ X, const float* __restrict__ Wt,
    const float* __restrict__ bias, const float* __restrict__ logs,
    unsigned int* __restrict__ outh, int n)
{
    __shared__ float xrow[4][RPW * 128];
    int tid = threadIdx.x;
    int wid = tid >> 6, lane = tid & 63;
    float2 bv = *(const float2*)(bias + 2 * lane);
    float sval = fminf(expf(logs[0]), 10.f);
    float* xbase = xrow[wid];
    const float* wcol = Wt + 2 * lane;
    int nslabs = (n + RPW - 1) / RPW;
    for (int slab = blockIdx.x * 4 + wid; slab < nslabs; slab += gridDim.x * 4) {
        int row0 = slab * RPW;
        #pragma unroll
        for (int r = 0; r < RPW; ++r) {
            int row = row0 + r;
            if (row >= n) {
                *(float2*)(xbase + r * 128 + 2 * lane) = make_float2(0.f, 0.f);
                continue;
            }
            if (PREEXP) {
                const float* src = X + (long)row * 127;
                float u0 = src[2 * lane];
                float u1 = (2 * lane + 1 < 127) ? src[2 * lane + 1] : 0.f;
                float ss = waveReduceSum(u0 * u0 + u1 * u1);
                float nrm = fmaxf(sqrtf(ss), EPSV);
                float ex = expf(nrm), exn = 1.f / ex;
                float ch = 0.5f * (ex + exn);
                float coef = (0.5f * (ex - exn)) / nrm;
                if (lane == 0) xbase[r * 128] = ch;
                xbase[r * 128 + 1 + 2 * lane] = coef * u0;
                if (2 * lane + 1 < 127) xbase[r * 128 + 2 + 2 * lane] = coef * u1;
            } else {
                float2 e = *(const float2*)(X + (long)row * 128 + 2 * lane);
                float t0 = __shfl(e.x, 0, 64);
                float ss = waveReduceSum(e.x * e.x + e.y * e.y);
                float neg_inner = 2.f * t0 * t0 - ss;
                float inv = 1.f / sqrtf(fmaxf(fabsf(neg_inner), EPSV));
                e.x = fmaxf(e.x * inv, 0.f);
                e.y = fmaxf(e.y * inv, 0.f);
                *(float2*)(xbase + r * 128 + 2 * lane) = e;
            }
        }
        float2 acc[RPW];
        #pragma unroll
        for (int r = 0; r < RPW; ++r) acc[r] = make_float2(0.f, 0.f);
        #pragma unroll 4
        for (int k0 = 0; k0 < 128; k0 += 4) {
            float2 w0 = *(const float2*)(wcol + (k0 + 0) * 128);
            float2 w1 = *(const float2*)(wcol + (k0 + 1) * 128);
            float2 w2 = *(const float2*)(wcol + (k0 + 2) * 128);
            float2 w3 = *(const float2*)(wcol + (k0 + 3) * 128);
            #pragma unroll
            for (int r = 0; r < RPW; ++r) {
                float4 xq = *(const float4*)(xbase + r * 128 + k0);
                acc[r].x = fmaf(xq.x, w0.x, acc[r].x);
                acc[r].y = fmaf(xq.x, w0.y, acc[r].y);
                acc[r].x = fmaf(xq.y, w1.x, acc[r].x);
                acc[r].y = fmaf(xq.y, w1.y, acc[r].y);
                acc[r].x = fmaf(xq.z, w2.x, acc[r].x);
                acc[r].y = fmaf(xq.z, w2.y, acc[r].y);
                acc[r].x = fmaf(xq.w, w3.x, acc[r].x);
                acc[r].y = fmaf(xq.w, w3.y, acc[r].y);
            }
        }
        #pragma unroll
        for (int r = 0; r < RPW; ++r) {
            int row = row0 + r;
            float ax = acc[r].x + bv.x;
            float ay = acc[r].y + bv.y;
            float t0 = __shfl(ax, 0, 64);
            float ssq = waveReduceSum(ax * ax + ay * ay);
            float timev = sval / (1.f + expf(-t0)) + 1.5f;
            float sq = fmaxf(ssq - t0 * t0, EPSV);
            float fac = sqrtf(fmaxf((timev * timev - 1.f) / sq, EPSV));
            if (row < n) {
                float o0 = (lane == 0) ? timev : ax * fac;
                float o1 = ay * fac;
                outh[(long)row * 64 + lane] = h_pack(o0, o1);
            }
        }
    }
}

// ---------------- CSR gather: 2 rows/wave, 4 edge-groups of 16 lanes ----------------
// Two interleaved edge loops (rows 2p, 2p+1) -> 2 independent load streams/wave.

#define GATHER_BODY(accs, idx, end)                                        \
    {                                                                      \
        int c = __builtin_nontemporal_load(&ecol_s[idx]);                  \
        float w = __builtin_nontemporal_load(&ew_s[idx]);                  \
        uint4 xw = *(const uint4*)(Xh + (long)c * 64 + l16 * 4);           \
        accs[0] = fmaf(w, h_lo(xw.x), accs[0]);                            \
        accs[1] = fmaf(w, h_hi(xw.x), accs[1]);                            \
        accs[2] = fmaf(w, h_lo(xw.y), accs[2]);                            \
        accs[3] = fmaf(w, h_hi(xw.y), accs[3]);                            \
        accs[4] = fmaf(w, h_lo(xw.z), accs[4]);                            \
        accs[5] = fmaf(w, h_hi(xw.z), accs[5]);                            \
        accs[6] = fmaf(w, h_lo(xw.w), accs[6]);                            \
        accs[7] = fmaf(w, h_hi(xw.w), accs[7]);                            \
    }

#define REDUCE8(accs)                                                      \
    _Pragma("unroll")                                                      \
    for (int q = 0; q < 8; ++q) {                                          \
        accs[q] += __shfl_xor(accs[q], 16, 64);                            \
        accs[q] += __shfl_xor(accs[q], 32, 64);                            \
    }

__global__ __launch_bounds__(256, 8) void gather_kernel(
    const unsigned int* __restrict__ Xh, const int* __restrict__ rs,
    const int* __restrict__ ecol_s, const float* __restrict__ ew_s,
    float* __restrict__ S, int n)
{
    int wid = threadIdx.x >> 6, lane = threadIdx.x & 63;
    int g = lane >> 4, l16 = lane & 15;
    int npairs = n >> 1;    // n even
    for (int pair = blockIdx.x * 4 + wid; pair < npairs; pair += gridDim.x * 4) {
        int rowA = 2 * pair, rowB = rowA + 1;
        int begA = rs[rowA], endA = rs[rowA + 1], endB = rs[rowB + 1];
        float aA[8] = {0,0,0,0,0,0,0,0};
        float aB[8] = {0,0,0,0,0,0,0,0};
        int ia = begA + g, ib = endA + g;    // begB == endA
        while (ia < endA && ib < endB) {
            GATHER_BODY(aA, ia, endA)
            GATHER_BODY(aB, ib, endB)
            ia += 4; ib += 4;
        }
        while (ia < endA) { GATHER_BODY(aA, ia, endA) ia += 4; }
        while (ib < endB) { GATHER_BODY(aB, ib, endB) ib += 4; }
        REDUCE8(aA)
        REDUCE8(aB)
        if (g == 0) {
            float* sp = S + (long)rowA * 128 + l16 * 8;
            *(float4*)sp       = make_float4(aA[0], aA[1], aA[2], aA[3]);
            *(float4*)(sp + 4) = make_float4(aA[4], aA[5], aA[6], aA[7]);
        } else if (g == 1) {
            float* sp = S + (long)rowB * 128 + l16 * 8;
            *(float4*)sp       = make_float4(aB[0], aB[1], aB[2], aB[3]);
            *(float4*)(sp + 4) = make_float4(aB[4], aB[5], aB[6], aB[7]);
        }
    }
}

// agg2 + lorentz-normalize + sign-flip + logits; 2 rows/wave; cls packed fp16 LDS
__global__ __launch_bounds__(256, 8) void gather_logits_kernel(
    const unsigned int* __restrict__ Xh, const int* __restrict__ rs,
    const int* __restrict__ ecol_s, const float* __restrict__ ew_s,
    const float* __restrict__ cls, const float* __restrict__ cbias,
    float* __restrict__ outp, int n)
{
    __shared__ unsigned int clsP[NCLS * 66];   // packed half2, stride 66 (2-way = free)
    __shared__ float cbS[NCLS];
    __shared__ float xsrow[4][2][128];
    int tid = threadIdx.x;
    for (int idx = tid; idx < NCLS * 64; idx += 256) {
        int c = idx >> 6, kk = idx & 63;
        clsP[c * 66 + kk] = h_pack(cls[c * 128 + 2 * kk], cls[c * 128 + 2 * kk + 1]);
    }
    if (tid < NCLS) cbS[tid] = cbias[tid];
    __syncthreads();
    int wid = tid >> 6, lane = tid & 63;
    int g = lane >> 4, l16 = lane & 15;
    float* xsA = xsrow[wid][0];
    float* xsB = xsrow[wid][1];
    int npairs = n >> 1;
    for (int pair = blockIdx.x * 4 + wid; pair < npairs; pair += gridDim.x * 4) {
        int rowA = 2 * pair, rowB = rowA + 1;
        int begA = rs[rowA], endA = rs[rowA + 1], endB = rs[rowB + 1];
        float aA[8] = {0,0,0,0,0,0,0,0};
        float aB[8] = {0,0,0,0,0,0,0,0};
        int ia = begA + g, ib = endA + g;
        while (ia < endA && ib < endB) {
            GATHER_BODY(aA, ia, endA)
            GATHER_BODY(aB, ib, endB)
            ia += 4; ib += 4;
        }
        while (ia < endA) { GATHER_BODY(aA, ia, endA) ia += 4; }
        while (ib < endB) { GATHER_BODY(aB, ib, endB) ib += 4; }
        REDUCE8(aA)
        REDUCE8(aB)
        // lorentz-normalize both rows (all lanes hold full totals)
        float ssA = aA[0]*aA[0]+aA[1]*aA[1]+aA[2]*aA[2]+aA[3]*aA[3]
                  + aA[4]*aA[4]+aA[5]*aA[5]+aA[6]*aA[6]+aA[7]*aA[7];
        float ssB = aB[0]*aB[0]+aB[1]*aB[1]+aB[2]*aB[2]+aB[3]*aB[3]
                  + aB[4]*aB[4]+aB[5]*aB[5]+aB[6]*aB[6]+aB[7]*aB[7];
        ssA += __shfl_xor(ssA, 1, 64); ssA += __shfl_xor(ssA, 2, 64);
        ssA += __shfl_xor(ssA, 4, 64); ssA += __shfl_xor(ssA, 8, 64);
        ssB += __shfl_xor(ssB, 1, 64); ssB += __shfl_xor(ssB, 2, 64);
        ssB += __shfl_xor(ssB, 4, 64); ssB += __shfl_xor(ssB, 8, 64);
        float t0A = bcastlane0(aA[0]);
        float t0B = bcastlane0(aB[0]);
        float invA = 1.f / sqrtf(fmaxf(fabsf(2.f * t0A * t0A - ssA), EPSV));
        float invB = 1.f / sqrtf(fmaxf(fabsf(2.f * t0B * t0B - ssB), EPSV));
        if (g == 0) {
            float v0 = aA[0] * invA;
            if (l16 == 0) v0 = -v0;
            float* xp = xsA + l16 * 8;
            *(float4*)xp       = make_float4(v0, aA[1]*invA, aA[2]*invA, aA[3]*invA);
            *(float4*)(xp + 4) = make_float4(aA[4]*invA, aA[5]*invA, aA[6]*invA, aA[7]*invA);
        } else if (g == 1) {
            float v0 = aB[0] * invB;
            if (l16 == 0) v0 = -v0;
            float* xp = xsB + l16 * 8;
            *(float4*)xp       = make_float4(v0, aB[1]*invB, aB[2]*invB, aB[3]*invB);
            *(float4*)(xp + 4) = make_float4(aB[4]*invB, aB[5]*invB, aB[6]*invB, aB[7]*invB);
        }
        // wave-private LDS: within-wave ordering, no barrier
        if (lane < NCLS) {
            float dA = 0.f, dB = 0.f;
            const unsigned int* cp = clsP + lane * 66;
            #pragma unroll 8
            for (int kk = 0; kk < 64; ++kk) {
                unsigned int u = cp[kk];
                float c0 = h_lo(u), c1 = h_hi(u);
                float2 xa = *(const float2*)(xsA + 2 * kk);
                float2 xb = *(const float2*)(xsB + 2 * kk);
                dA = fmaf(c0, xa.x, dA); dA = fmaf(c1, xa.y, dA);
                dB = fmaf(c0, xb.x, dB); dB = fmaf(c1, xb.y, dB);
            }
            outp[(long)rowA * NCLS + lane] = 2.f + 2.f * dA + cbS[lane];
            outp[(long)rowB * NCLS + lane] = 2.f + 2.f * dB + cbS[lane];
        }
    }
}

// ---------------- launch ----------------

extern "C" void kernel_launch(void* const* d_in, const int* in_sizes, int n_in,
                              void* d_out, int out_size, void* d_ws, size_t ws_size,
                              hipStream_t stream) {
    const float* node_feat = (const float*)d_in[0];
    const float* W1   = (const float*)d_in[1];
    const float* b1   = (const float*)d_in[2];
    const float* s1   = (const float*)d_in[3];
    const float* W2   = (const float*)d_in[4];
    const float* b2   = (const float*)d_in[5];
    const float* s2   = (const float*)d_in[6];
    const float* cls  = (const float*)d_in[7];
    const float* cb   = (const float*)d_in[8];
    const float* ew   = (const float*)d_in[9];
    const int*   erow = (const int*)d_in[10];
    const int*   ecol = (const int*)d_in[11];
    float* outp = (float*)d_out;

    const int n = NN;
    const int E = in_sizes[9];
    const int NBLK = (NN + 255) / 256;   // 196

    float*        bufB  = (float*)d_ws;                              // NN*128 fp32
    unsigned int* bufH  = (unsigned int*)(bufB + (size_t)NN * 128);  // NN*64 uint (fp16 X)
    int*   rs     = (int*)(bufH + (size_t)NN * 64);
    int*   pos    = rs + (NN + 1);
    int*   bsum   = pos + NN;
    int*   ecol_s = bsum + 256;
    float* ew_s   = (float*)(ecol_s + E);
    float* wt1    = ew_s + E;
    float* wt2    = wt1 + 128 * 128;

    // CSR build + W transposes
    (void)hipMemsetAsync(pos, 0, (size_t)NN * sizeof(int), stream);
    transpose128<<<64, 256, 0, stream>>>(W1, wt1);
    transpose128<<<64, 256, 0, stream>>>(W2, wt2);
    hist_kernel<<<2048, 256, 0, stream>>>(erow, pos, E);
    scan1_kernel<<<NBLK, 256, 0, stream>>>(pos, rs, bsum, n);
    scan2_kernel<<<1, 256, 0, stream>>>(bsum, NBLK);
    scan3_kernel<<<NBLK, 256, 0, stream>>>(rs, bsum, n, E);
    (void)hipMemcpyAsync(pos, rs, (size_t)NN * sizeof(int), hipMemcpyDeviceToDevice, stream);
    fill_kernel<<<2048, 256, 0, stream>>>(erow, ecol, ew, pos, ecol_s, ew_s, E);

    const int nslabs = (n + RPW - 1) / RPW;     // 6250
    const int LGRID = (nslabs + 3) / 4;         // 1563
    const int PGRID = ((n >> 1) + 3) / 4;       // 6250 (row pairs)

    // pipeline
    linear_lorentz<1><<<LGRID, 256, 0, stream>>>(node_feat, wt1, b1, s1, bufH, n);  // expmap+L1 -> fp16
    gather_kernel<<<PGRID, 256, 0, stream>>>(bufH, rs, ecol_s, ew_s, bufB, n);      // agg1 -> fp32
    linear_lorentz<0><<<LGRID, 256, 0, stream>>>(bufB, wt2, b2, s2, bufH, n);       // norm+relu+L2 -> fp16
    gather_logits_kernel<<<PGRID, 256, 0, stream>>>(bufH, rs, ecol_s, ew_s, cls, cb, outp, n); // agg2+logits
}